// Round 11
// baseline (762.558 us; speedup 1.0000x reference)
//
#include <hip/hip_runtime.h>
#include <hip/hip_bf16.h>
#include <hip/hip_cooperative_groups.h>
#include <math.h>

namespace cg = cooperative_groups;

#define NEG_SLOPE 0.2f

typedef __attribute__((ext_vector_type(8))) short short8v;   // 8 bf16
typedef __attribute__((ext_vector_type(4))) float f32x4;

__device__ __forceinline__ float bfu2f(unsigned short u) {
    return __uint_as_float((unsigned)u << 16);
}

// ---------------- merged prep: x cast + weight transposes + projections + cnt zero ----

__device__ __forceinline__ void trans1(const float* __restrict__ W,
                                       __hip_bfloat16* __restrict__ WT,
                                       int K, int N, int t) {
    int n = t / K, k = t - n * K;
    WT[t] = __float2bfloat16(W[(long)k * N + n]);
}

__device__ __forceinline__ void wext1(const float* __restrict__ W,
                                      const float* __restrict__ as,
                                      const float* __restrict__ ad,
                                      __hip_bfloat16* __restrict__ WT,
                                      int K, int HC, int C, int t) {
    int r = t / K, k = t - r * K;
    int h = r >> 1;
    const float* av = ((r & 1) ? ad : as) + h * C;
    const float* wp = W + (long)k * HC + h * C;
    float s = 0.f;
    for (int c = 0; c < C; ++c) s += av[c] * wp[c];
    WT[(long)(HC + r) * K + k] = __float2bfloat16(s);
}

__global__ void prep_all(const float* __restrict__ x, __hip_bfloat16* __restrict__ xb,
                         long nx4,
                         const float* __restrict__ W1, const float* __restrict__ a1s,
                         const float* __restrict__ a1d, const float* __restrict__ W2,
                         const float* __restrict__ a2s, const float* __restrict__ a2d,
                         const float* __restrict__ W3, const float* __restrict__ a3s,
                         const float* __restrict__ a3d,
                         __hip_bfloat16* __restrict__ W1T, __hip_bfloat16* __restrict__ W2T,
                         __hip_bfloat16* __restrict__ W3T,
                         int* __restrict__ cnt, int N) {
    long t = (long)blockIdx.x * blockDim.x + threadIdx.x;
    if (t < nx4) {
        long i = t * 4;
        float4 v = *(const float4*)(x + i);
        __hip_bfloat162* o = (__hip_bfloat162*)(xb + i);
        o[0] = __hip_bfloat162{__float2bfloat16(v.x), __float2bfloat16(v.y)};
        o[1] = __hip_bfloat162{__float2bfloat16(v.z), __float2bfloat16(v.w)};
        return;
    }
    int u = (int)(t - nx4);
    if (u < 98304)       trans1(W1, W1T, 256, 384, u);
    else if (u < 147456) trans1(W2, W2T, 384, 128, u - 98304);
    else if (u < 155648) trans1(W3, W3T, 128, 64, u - 147456);
    else if (u < 157696) wext1(W1, a1s, a1d, W1T, 256, 384, 96, u - 155648);
    else if (u < 158464) wext1(W2, a2s, a2d, W2T, 384, 128, 128, u - 157696);
    else if (u < 158720) wext1(W3, a3s, a3d, W3T, 128, 64, 64, u - 158464);
    else { int i = u - 158720; if (i < N) cnt[i] = 0; }
}

// ---------------- MFMA bf16 GEMM (128x64 tile, BK=32) with attention epilogue --------
__global__ __launch_bounds__(256) void gemm_bf16(
        const __hip_bfloat16* __restrict__ A, const __hip_bfloat16* __restrict__ BT,
        __hip_bfloat16* __restrict__ Cb,
        float* __restrict__ asv, float* __restrict__ adv,
        int M, int K, int Nlog, int HC, int Hh) {
    __shared__ __align__(16) __hip_bfloat16 As[128][40];   // +8 pad: 2-way reads (free)
    __shared__ __align__(16) __hip_bfloat16 Bs[64][40];
    int t = threadIdx.x;
    int wave = t >> 6, lane = t & 63;
    int wm = wave >> 1, wn = wave & 1;              // 2x2 waves: wave tile 64x32
    int m0 = blockIdx.y * 128, n0 = blockIdx.x * 64;
    int lrow = lane & 15, kb = lane >> 4;

    f32x4 acc[4][2] = {};
    int arow = t >> 1, acol = (t & 1) * 16;
    int brow = t >> 2, bcol = (t & 3) * 8;

    for (int k0 = 0; k0 < K; k0 += 32) {
        int gr = m0 + arow;
        short8v av0 = {}, av1 = {};
        if (gr < M) {
            const __hip_bfloat16* ap = A + (long)gr * K + k0 + acol;
            av0 = *(const short8v*)ap;
            av1 = *(const short8v*)(ap + 8);
        }
        int gn = n0 + brow;
        short8v bv = {};
        if (gn < Nlog) bv = *(const short8v*)(BT + (long)gn * K + k0 + bcol);
        __syncthreads();
        *(short8v*)&As[arow][acol] = av0;
        *(short8v*)&As[arow][acol + 8] = av1;
        *(short8v*)&Bs[brow][bcol] = bv;
        __syncthreads();
        short8v b0 = *(const short8v*)&Bs[wn * 32 + lrow][kb * 8];
        short8v b1 = *(const short8v*)&Bs[wn * 32 + 16 + lrow][kb * 8];
#pragma unroll
        for (int i = 0; i < 4; ++i) {
            short8v a = *(const short8v*)&As[wm * 64 + i * 16 + lrow][kb * 8];
            acc[i][0] = __builtin_amdgcn_mfma_f32_16x16x32_bf16(a, b0, acc[i][0], 0, 0, 0);
            acc[i][1] = __builtin_amdgcn_mfma_f32_16x16x32_bf16(a, b1, acc[i][1], 0, 0, 0);
        }
    }
#pragma unroll
    for (int i = 0; i < 4; ++i)
#pragma unroll
        for (int j = 0; j < 2; ++j) {
            int col = n0 + wn * 32 + j * 16 + lrow;
            if (col >= Nlog) continue;
#pragma unroll
            for (int r = 0; r < 4; ++r) {
                int row = m0 + wm * 64 + i * 16 + kb * 4 + r;
                if (row >= M) continue;
                float v = acc[i][j][r];
                if (col < HC) {
                    Cb[(long)row * HC + col] = __float2bfloat16(v);
                } else {
                    int f = col - HC, h = f >> 1;
                    if (f & 1) adv[row * Hh + h] = v;
                    else       asv[row * Hh + h] = v;
                }
            }
        }
}

// ---------------- cooperative CSR build (hist + scan + fill in one kernel) -----------
__global__ void csr_build(const int* __restrict__ src, const int* __restrict__ dst,
                          int* __restrict__ cnt, int* __restrict__ rowptr,
                          int* __restrict__ bsum, int* __restrict__ esrc,
                          int E, int Etot, int N, int nb) {
    cg::grid_group grid = cg::this_grid();
    const int gsize = gridDim.x * blockDim.x;
    const int gtid  = blockIdx.x * blockDim.x + threadIdx.x;
    __shared__ int s[256];

    // phase A: histogram of dst (cnt pre-zeroed by prep_all)
    for (int e = gtid; e < Etot; e += gsize) {
        int d = (e < E) ? dst[e] : (e - E);
        atomicAdd(&cnt[d], 1);
    }
    grid.sync();

    // phase B1: per-tile (256) exclusive scan -> rowptr partials, tile sums -> bsum
    for (int tile = blockIdx.x; tile < nb; tile += gridDim.x) {
        int i = tile * 256 + threadIdx.x;
        int v = (i < N) ? cnt[i] : 0;
        __syncthreads();
        s[threadIdx.x] = v;
        __syncthreads();
        for (int off = 1; off < 256; off <<= 1) {
            int t2 = (threadIdx.x >= off) ? s[threadIdx.x - off] : 0;
            __syncthreads();
            s[threadIdx.x] += t2;
            __syncthreads();
        }
        if (i < N) rowptr[i] = s[threadIdx.x] - v;
        if (threadIdx.x == 255) bsum[tile] = s[255];
    }
    grid.sync();

    // phase B2: single-block exclusive scan of bsum (nb <= 256)
    if (blockIdx.x == 0) {
        int v = (threadIdx.x < nb) ? bsum[threadIdx.x] : 0;
        s[threadIdx.x] = v;
        __syncthreads();
        for (int off = 1; off < 256; off <<= 1) {
            int t2 = (threadIdx.x >= off) ? s[threadIdx.x - off] : 0;
            __syncthreads();
            s[threadIdx.x] += t2;
            __syncthreads();
        }
        if (threadIdx.x < nb) bsum[threadIdx.x] = s[threadIdx.x] - v;
    }
    grid.sync();

    // phase B3: add tile offsets; zero cnt (reused as cursor); rowptr[N]
    for (int i = gtid; i < N; i += gsize) {
        rowptr[i] += bsum[i >> 8];
        cnt[i] = 0;
    }
    if (gtid == 0) rowptr[N] = Etot;
    grid.sync();

    // phase C: fill slot-sorted esrc
    for (int e = gtid; e < Etot; e += gsize) {
        int sv = (e < E) ? src[e] : (e - E);
        int d  = (e < E) ? dst[e] : (e - E);
        int pos = atomicAdd(&cnt[d], 1);
        esrc[rowptr[d] + pos] = sv;
    }
}

// ---------------- wave-per-node fused softmax + gather ----------------
template <int HH, int C, bool FUSE>
__global__ __launch_bounds__(256) void gat_gather_wave(
        const int* __restrict__ rowptr, const int* __restrict__ esrc,
        const __hip_bfloat16* __restrict__ H,
        const float* __restrict__ asv, const float* __restrict__ adv,
        const float* __restrict__ bias, __hip_bfloat16* __restrict__ out,
        int act, int N,
        const float* __restrict__ Wcf, const float* __restrict__ bcf,
        float* __restrict__ outf) {
    constexpr int HC  = HH * C;
    constexpr int TPE = HC / 8;
    constexpr int EPW0 = 64 / TPE;
    constexpr int EPW = EPW0 < 1 ? 1 : (EPW0 > 8 ? 8 : EPW0);
    constexpr int WPB = 4;

    __shared__ float sAlA[WPB][HH][72];
    __shared__ int   sSrcA[WPB][64];
    __shared__ float sWc[FUSE ? 64 * 40 : 1];
    __shared__ float sHA[FUSE ? WPB : 1][64];

    if constexpr (FUSE) {
        for (int i = threadIdx.x; i < 64 * 40; i += 256) sWc[i] = Wcf[i];
        __syncthreads();
    }

    const int wid  = threadIdx.x >> 6;
    const int lane = threadIdx.x & 63;
    const int d = blockIdx.x * WPB + wid;
    if (d >= N) return;

    float (*sAl)[72] = sAlA[wid];
    int* sSrc = sSrcA[wid];

    const int begin = rowptr[d], end = rowptr[d + 1];
    float adn[HH];
#pragma unroll
    for (int h = 0; h < HH; ++h) adn[h] = adv[d * HH + h];

    const bool act_g = (lane < TPE * EPW);
    const int g  = lane / TPE;
    const int tq = lane % TPE;
    const int c8 = tq * 8;
    const int hc = c8 / C;
    float acc[8] = {};
    float s_lane[HH];
#pragma unroll
    for (int h = 0; h < HH; ++h) s_lane[h] = 0.f;

    for (int chunk = begin; chunk < end; chunk += 64) {
        int n = end - chunk; if (n > 64) n = 64;
        if (lane < n) {
            int s = esrc[chunk + lane];
            sSrc[lane] = s;
            if (HH == 4) {
                float4 a4 = *(const float4*)(asv + s * 4);
                float vv[4] = {a4.x, a4.y, a4.z, a4.w};
#pragma unroll
                for (int h = 0; h < HH; ++h) {
                    float v = vv[h] + adn[h];
                    v = (v > 0.f) ? v : NEG_SLOPE * v;
                    float p = __expf(fminf(v, 60.f));
                    sAl[h][lane] = p;
                    s_lane[h] += p;
                }
            } else {
                float v = asv[s] + adn[0];
                v = (v > 0.f) ? v : NEG_SLOPE * v;
                float p = __expf(fminf(v, 60.f));
                sAl[0][lane] = p;
                s_lane[0] += p;
            }
        }
        if (act_g) {
            int k = g;
            bool have = (k < n);
            float pc = 0.f; short8v vc = {};
            if (have) {
                pc = sAl[hc][k];
                vc = *(const short8v*)(H + (long)sSrc[k] * HC + c8);
            }
            while (have) {
                int k1 = k + EPW;
                bool h1 = (k1 < n);
                float p1 = 0.f; short8v v1 = {};
                if (h1) {
                    p1 = sAl[hc][k1];
                    v1 = *(const short8v*)(H + (long)sSrc[k1] * HC + c8);
                }
#pragma unroll
                for (int j = 0; j < 8; ++j)
                    acc[j] += pc * bfu2f((unsigned short)vc[j]);
                k = k1; pc = p1; vc = v1; have = h1;
            }
        }
    }

    if constexpr (EPW > 1) {
#pragma unroll
        for (int m = TPE; m < 64; m <<= 1)
#pragma unroll
            for (int j = 0; j < 8; ++j) acc[j] += __shfl_xor(acc[j], m);
    }

    float den[HH];
#pragma unroll
    for (int h = 0; h < HH; ++h) {
        float sl = s_lane[h];
#pragma unroll
        for (int m = 1; m < 64; m <<= 1) sl += __shfl_xor(sl, m);
        den[h] = sl + 1e-16f;
    }

    if (lane < TPE) {
        float inv = 1.0f / den[hc];
        float4 b0 = *(const float4*)(bias + c8);
        float4 b1 = *(const float4*)(bias + c8 + 4);
        float bb[8] = {b0.x, b0.y, b0.z, b0.w, b1.x, b1.y, b1.z, b1.w};
        float rr[8];
#pragma unroll
        for (int j = 0; j < 8; ++j) {
            float r = acc[j] * inv + bb[j];
            if (act == 1) r = fmaxf(r, 0.f);
            else if (act == 2) r = tanhf(r);
            rr[j] = r;
        }
        if constexpr (FUSE) {
#pragma unroll
            for (int j = 0; j < 8; ++j) sHA[wid][c8 + j] = rr[j];
        } else {
            short8v o;
#pragma unroll
            for (int j = 0; j < 8; ++j)
                o[j] = (short)__bfloat16_as_ushort(__float2bfloat16(rr[j]));
            *(short8v*)(out + (long)d * HC + c8) = o;
        }
    }

    if constexpr (FUSE) {
        if (lane < 40) {
            float o = bcf[lane];
#pragma unroll 8
            for (int c = 0; c < 64; ++c) o += sHA[wid][c] * sWc[c * 40 + lane];
            outf[(long)d * 40 + lane] = o;
        }
    }
}

// ---------------- launch ----------------

extern "C" void kernel_launch(void* const* d_in, const int* in_sizes, int n_in,
                              void* d_out, int out_size, void* d_ws, size_t ws_size,
                              hipStream_t stream) {
    const float* x    = (const float*)d_in[0];
    const int*   ei   = (const int*)d_in[1];
    const float* W1   = (const float*)d_in[2];
    const float* a1s  = (const float*)d_in[3];
    const float* a1d  = (const float*)d_in[4];
    const float* b1   = (const float*)d_in[5];
    const float* W2   = (const float*)d_in[6];
    const float* a2s  = (const float*)d_in[7];
    const float* a2d  = (const float*)d_in[8];
    const float* b2   = (const float*)d_in[9];
    const float* W3   = (const float*)d_in[10];
    const float* a3s  = (const float*)d_in[11];
    const float* a3d  = (const float*)d_in[12];
    const float* b3   = (const float*)d_in[13];
    const float* Wc   = (const float*)d_in[14];
    const float* bc   = (const float*)d_in[15];

    const int F0 = 256;
    int N = in_sizes[0] / F0;          // 50000
    int E = in_sizes[1] / 2;           // 800000
    int Etot = E + N;
    const int* srcI = ei;
    const int* dstI = ei + E;

    // ---- workspace carve ----
    char* p = (char*)d_ws;
    auto alloc = [&](size_t bytes) { void* r = p; p += (bytes + 255) & ~(size_t)255; return r; };
    __hip_bfloat16* xb  = (__hip_bfloat16*)alloc((size_t)N * 256 * 2);
    __hip_bfloat16* Hb  = (__hip_bfloat16*)alloc((size_t)N * 384 * 2);
    __hip_bfloat16* O1  = (__hip_bfloat16*)alloc((size_t)N * 384 * 2);
    __hip_bfloat16* O2  = (__hip_bfloat16*)alloc((size_t)N * 128 * 2);
    __hip_bfloat16* W1T = (__hip_bfloat16*)alloc((size_t)(384 + 8) * 256 * 2);
    __hip_bfloat16* W2T = (__hip_bfloat16*)alloc((size_t)(128 + 2) * 384 * 2);
    __hip_bfloat16* W3T = (__hip_bfloat16*)alloc((size_t)(64 + 2) * 128 * 2);
    float* as_  = (float*)alloc((size_t)N * 4 * 4);
    float* ad_  = (float*)alloc((size_t)N * 4 * 4);
    int* rowptr = (int*)alloc((size_t)(N + 1) * 4);
    int* cnt    = (int*)alloc((size_t)N * 4);
    int* esrc   = (int*)alloc((size_t)Etot * 4);
    int* bsum   = (int*)alloc(256 * 4);

    // ---- merged prep (x cast + weights + projections + cnt zero) ----
    long nx4 = (long)N * 256 / 4;                 // 3.2M
    long ptot = nx4 + 158720 + N;
    prep_all<<<(int)((ptot + 255) / 256), 256, 0, stream>>>(
        x, xb, nx4, W1, a1s, a1d, W2, a2s, a2d, W3, a3s, a3d,
        W1T, W2T, W3T, cnt, N);

    // ---- cooperative CSR build (one kernel, grid syncs between phases) ----
    int nb = (N + 255) / 256;          // 196 tiles (<= 256)
    {
        void* args[] = {(void*)&srcI, (void*)&dstI, (void*)&cnt, (void*)&rowptr,
                        (void*)&bsum, (void*)&esrc, (void*)&E, (void*)&Etot,
                        (void*)&N, (void*)&nb};
        hipLaunchCooperativeKernel((const void*)csr_build, dim3(1024), dim3(256),
                                   args, 0, stream);
    }

    auto run_gemm = [&](const __hip_bfloat16* X, int Fin, const __hip_bfloat16* WT,
                        int Hh, int C, __hip_bfloat16* Hout) {
        int HC = Hh * C;
        int Nlog = HC + 2 * Hh;
        dim3 gg((Nlog + 63) / 64, (N + 127) / 128);
        gemm_bf16<<<gg, 256, 0, stream>>>(X, WT, Hout, as_, ad_, N, Fin, Nlog, HC, Hh);
    };
    int gwb = (N + 3) / 4;   // 4 nodes (waves) per block
    float* out = (float*)d_out;

    // Layer 1: 256 -> 4x96, relu
    run_gemm(xb, 256, W1T, 4, 96, Hb);
    gat_gather_wave<4, 96, false><<<gwb, 256, 0, stream>>>(
        rowptr, esrc, Hb, as_, ad_, b1, O1, 1, N, nullptr, nullptr, nullptr);
    // Layer 2: 384 -> 1x128, tanh
    run_gemm(O1, 384, W2T, 1, 128, Hb);
    gat_gather_wave<1, 128, false><<<gwb, 256, 0, stream>>>(
        rowptr, esrc, Hb, as_, ad_, b2, O2, 2, N, nullptr, nullptr, nullptr);
    // Layer 3: 128 -> 1x64, tanh + fused classifier (64x40 matvec, f32 out)
    run_gemm(O2, 128, W3T, 1, 64, Hb);
    gat_gather_wave<1, 64, true><<<gwb, 256, 0, stream>>>(
        rowptr, esrc, Hb, as_, ad_, b3, nullptr, 2, N, Wc, bc, out);
}

// Round 12
// 376.866 us; speedup vs baseline: 2.0234x; 2.0234x over previous
//
#include <hip/hip_runtime.h>
#include <hip/hip_bf16.h>
#include <math.h>

#define NEG_SLOPE 0.2f

typedef __attribute__((ext_vector_type(8))) short short8v;   // 8 bf16
typedef __attribute__((ext_vector_type(4))) float f32x4;

__device__ __forceinline__ float bfu2f(unsigned short u) {
    return __uint_as_float((unsigned)u << 16);
}

// ---------------- merged prep: x cast + weight transposes + projections + cnt zero ----

__device__ __forceinline__ void trans1(const float* __restrict__ W,
                                       __hip_bfloat16* __restrict__ WT,
                                       int K, int N, int t) {
    int n = t / K, k = t - n * K;
    WT[t] = __float2bfloat16(W[(long)k * N + n]);
}

__device__ __forceinline__ void wext1(const float* __restrict__ W,
                                      const float* __restrict__ as,
                                      const float* __restrict__ ad,
                                      __hip_bfloat16* __restrict__ WT,
                                      int K, int HC, int C, int t) {
    int r = t / K, k = t - r * K;
    int h = r >> 1;
    const float* av = ((r & 1) ? ad : as) + h * C;
    const float* wp = W + (long)k * HC + h * C;
    float s = 0.f;
    for (int c = 0; c < C; ++c) s += av[c] * wp[c];
    WT[(long)(HC + r) * K + k] = __float2bfloat16(s);
}

__global__ void prep_all(const float* __restrict__ x, __hip_bfloat16* __restrict__ xb,
                         long nx4,
                         const float* __restrict__ W1, const float* __restrict__ a1s,
                         const float* __restrict__ a1d, const float* __restrict__ W2,
                         const float* __restrict__ a2s, const float* __restrict__ a2d,
                         const float* __restrict__ W3, const float* __restrict__ a3s,
                         const float* __restrict__ a3d,
                         __hip_bfloat16* __restrict__ W1T, __hip_bfloat16* __restrict__ W2T,
                         __hip_bfloat16* __restrict__ W3T,
                         int* __restrict__ cnt, int N) {
    long t = (long)blockIdx.x * blockDim.x + threadIdx.x;
    if (t < nx4) {
        long i = t * 4;
        float4 v = *(const float4*)(x + i);
        __hip_bfloat162* o = (__hip_bfloat162*)(xb + i);
        o[0] = __hip_bfloat162{__float2bfloat16(v.x), __float2bfloat16(v.y)};
        o[1] = __hip_bfloat162{__float2bfloat16(v.z), __float2bfloat16(v.w)};
        return;
    }
    int u = (int)(t - nx4);
    if (u < 98304)       trans1(W1, W1T, 256, 384, u);
    else if (u < 147456) trans1(W2, W2T, 384, 128, u - 98304);
    else if (u < 155648) trans1(W3, W3T, 128, 64, u - 147456);
    else if (u < 157696) wext1(W1, a1s, a1d, W1T, 256, 384, 96, u - 155648);
    else if (u < 158464) wext1(W2, a2s, a2d, W2T, 384, 128, 128, u - 157696);
    else if (u < 158720) wext1(W3, a3s, a3d, W3T, 128, 64, 64, u - 158464);
    else { int i = u - 158720; if (i < N) cnt[i] = 0; }
}

// ---------------- MFMA bf16 GEMM (128x64 tile, BK=32) with attention epilogue --------
__global__ __launch_bounds__(256) void gemm_bf16(
        const __hip_bfloat16* __restrict__ A, const __hip_bfloat16* __restrict__ BT,
        __hip_bfloat16* __restrict__ Cb,
        float* __restrict__ asv, float* __restrict__ adv,
        int M, int K, int Nlog, int HC, int Hh) {
    __shared__ __align__(16) __hip_bfloat16 As[128][40];   // +8 pad: 2-way reads (free)
    __shared__ __align__(16) __hip_bfloat16 Bs[64][40];
    int t = threadIdx.x;
    int wave = t >> 6, lane = t & 63;
    int wm = wave >> 1, wn = wave & 1;              // 2x2 waves: wave tile 64x32
    int m0 = blockIdx.y * 128, n0 = blockIdx.x * 64;
    int lrow = lane & 15, kb = lane >> 4;

    f32x4 acc[4][2] = {};
    int arow = t >> 1, acol = (t & 1) * 16;
    int brow = t >> 2, bcol = (t & 3) * 8;

    for (int k0 = 0; k0 < K; k0 += 32) {
        int gr = m0 + arow;
        short8v av0 = {}, av1 = {};
        if (gr < M) {
            const __hip_bfloat16* ap = A + (long)gr * K + k0 + acol;
            av0 = *(const short8v*)ap;
            av1 = *(const short8v*)(ap + 8);
        }
        int gn = n0 + brow;
        short8v bv = {};
        if (gn < Nlog) bv = *(const short8v*)(BT + (long)gn * K + k0 + bcol);
        __syncthreads();
        *(short8v*)&As[arow][acol] = av0;
        *(short8v*)&As[arow][acol + 8] = av1;
        *(short8v*)&Bs[brow][bcol] = bv;
        __syncthreads();
        short8v b0 = *(const short8v*)&Bs[wn * 32 + lrow][kb * 8];
        short8v b1 = *(const short8v*)&Bs[wn * 32 + 16 + lrow][kb * 8];
#pragma unroll
        for (int i = 0; i < 4; ++i) {
            short8v a = *(const short8v*)&As[wm * 64 + i * 16 + lrow][kb * 8];
            acc[i][0] = __builtin_amdgcn_mfma_f32_16x16x32_bf16(a, b0, acc[i][0], 0, 0, 0);
            acc[i][1] = __builtin_amdgcn_mfma_f32_16x16x32_bf16(a, b1, acc[i][1], 0, 0, 0);
        }
    }
#pragma unroll
    for (int i = 0; i < 4; ++i)
#pragma unroll
        for (int j = 0; j < 2; ++j) {
            int col = n0 + wn * 32 + j * 16 + lrow;
            if (col >= Nlog) continue;
#pragma unroll
            for (int r = 0; r < 4; ++r) {
                int row = m0 + wm * 64 + i * 16 + kb * 4 + r;
                if (row >= M) continue;
                float v = acc[i][j][r];
                if (col < HC) {
                    Cb[(long)row * HC + col] = __float2bfloat16(v);
                } else {
                    int f = col - HC, h = f >> 1;
                    if (f & 1) adv[row * Hh + h] = v;
                    else       asv[row * Hh + h] = v;
                }
            }
        }
}

// ---------------- CSR build (5 small dispatches — measured faster than coop) ---------

__global__ void hist_kernel(const int* __restrict__ dst, int* __restrict__ cnt,
                            int E, int Etot) {
    int e = blockIdx.x * blockDim.x + threadIdx.x;
    if (e >= Etot) return;
    int d = (e < E) ? dst[e] : (e - E);
    atomicAdd(&cnt[d], 1);
}

__global__ void scan1(const int* __restrict__ cnt, int* __restrict__ rowptr,
                      int* __restrict__ bsum, int n) {
    __shared__ int s[256];
    int i = blockIdx.x * 256 + threadIdx.x;
    int v = (i < n) ? cnt[i] : 0;
    s[threadIdx.x] = v;
    __syncthreads();
    for (int off = 1; off < 256; off <<= 1) {
        int t = (threadIdx.x >= off) ? s[threadIdx.x - off] : 0;
        __syncthreads();
        s[threadIdx.x] += t;
        __syncthreads();
    }
    if (i < n) rowptr[i] = s[threadIdx.x] - v;
    if (threadIdx.x == 255) bsum[blockIdx.x] = s[255];
}

__global__ void scan2(int* __restrict__ bsum, int nb) {
    __shared__ int s[256];
    int v = (threadIdx.x < nb) ? bsum[threadIdx.x] : 0;
    s[threadIdx.x] = v;
    __syncthreads();
    for (int off = 1; off < 256; off <<= 1) {
        int t = (threadIdx.x >= off) ? s[threadIdx.x - off] : 0;
        __syncthreads();
        s[threadIdx.x] += t;
        __syncthreads();
    }
    if (threadIdx.x < nb) bsum[threadIdx.x] = s[threadIdx.x] - v;
}

__global__ void scan3(int* __restrict__ rowptr, const int* __restrict__ bsum,
                      int* __restrict__ cnt, int n, int Etot) {
    int i = blockIdx.x * 256 + threadIdx.x;
    if (i < n) {
        rowptr[i] += bsum[blockIdx.x];
        cnt[i] = 0;
    }
    if (i == 0) rowptr[n] = Etot;
}

__global__ void fill_kernel(const int* __restrict__ src, const int* __restrict__ dst,
                            const int* __restrict__ rowptr, int* __restrict__ cursor,
                            int* __restrict__ esrc, int E, int Etot) {
    int e = blockIdx.x * blockDim.x + threadIdx.x;
    if (e >= Etot) return;
    int s = (e < E) ? src[e] : (e - E);
    int d = (e < E) ? dst[e] : (e - E);
    int pos = atomicAdd(&cursor[d], 1);
    esrc[rowptr[d] + pos] = s;
}

// ---------------- wave-per-node fused softmax + gather ----------------
template <int HH, int C, bool FUSE>
__global__ __launch_bounds__(256) void gat_gather_wave(
        const int* __restrict__ rowptr, const int* __restrict__ esrc,
        const __hip_bfloat16* __restrict__ H,
        const float* __restrict__ asv, const float* __restrict__ adv,
        const float* __restrict__ bias, __hip_bfloat16* __restrict__ out,
        int act, int N,
        const float* __restrict__ Wcf, const float* __restrict__ bcf,
        float* __restrict__ outf) {
    constexpr int HC  = HH * C;
    constexpr int TPE = HC / 8;
    constexpr int EPW0 = 64 / TPE;
    constexpr int EPW = EPW0 < 1 ? 1 : (EPW0 > 8 ? 8 : EPW0);
    constexpr int WPB = 4;

    __shared__ float sAlA[WPB][HH][72];
    __shared__ int   sSrcA[WPB][64];
    __shared__ float sWc[FUSE ? 64 * 40 : 1];
    __shared__ float sHA[FUSE ? WPB : 1][64];

    if constexpr (FUSE) {
        for (int i = threadIdx.x; i < 64 * 40; i += 256) sWc[i] = Wcf[i];
        __syncthreads();
    }

    const int wid  = threadIdx.x >> 6;
    const int lane = threadIdx.x & 63;
    const int d = blockIdx.x * WPB + wid;
    if (d >= N) return;

    float (*sAl)[72] = sAlA[wid];
    int* sSrc = sSrcA[wid];

    const int begin = rowptr[d], end = rowptr[d + 1];
    float adn[HH];
#pragma unroll
    for (int h = 0; h < HH; ++h) adn[h] = adv[d * HH + h];

    const bool act_g = (lane < TPE * EPW);
    const int g  = lane / TPE;
    const int tq = lane % TPE;
    const int c8 = tq * 8;
    const int hc = c8 / C;
    float acc[8] = {};
    float s_lane[HH];
#pragma unroll
    for (int h = 0; h < HH; ++h) s_lane[h] = 0.f;

    for (int chunk = begin; chunk < end; chunk += 64) {
        int n = end - chunk; if (n > 64) n = 64;
        if (lane < n) {
            int s = esrc[chunk + lane];
            sSrc[lane] = s;
            if (HH == 4) {
                float4 a4 = *(const float4*)(asv + s * 4);
                float vv[4] = {a4.x, a4.y, a4.z, a4.w};
#pragma unroll
                for (int h = 0; h < HH; ++h) {
                    float v = vv[h] + adn[h];
                    v = (v > 0.f) ? v : NEG_SLOPE * v;
                    float p = __expf(fminf(v, 60.f));
                    sAl[h][lane] = p;
                    s_lane[h] += p;
                }
            } else {
                float v = asv[s] + adn[0];
                v = (v > 0.f) ? v : NEG_SLOPE * v;
                float p = __expf(fminf(v, 60.f));
                sAl[0][lane] = p;
                s_lane[0] += p;
            }
        }
        if (act_g) {
            int k = g;
            bool have = (k < n);
            float pc = 0.f; short8v vc = {};
            if (have) {
                pc = sAl[hc][k];
                vc = *(const short8v*)(H + (long)sSrc[k] * HC + c8);
            }
            while (have) {
                int k1 = k + EPW;
                bool h1 = (k1 < n);
                float p1 = 0.f; short8v v1 = {};
                if (h1) {
                    p1 = sAl[hc][k1];
                    v1 = *(const short8v*)(H + (long)sSrc[k1] * HC + c8);
                }
#pragma unroll
                for (int j = 0; j < 8; ++j)
                    acc[j] += pc * bfu2f((unsigned short)vc[j]);
                k = k1; pc = p1; vc = v1; have = h1;
            }
        }
    }

    if constexpr (EPW > 1) {
#pragma unroll
        for (int m = TPE; m < 64; m <<= 1)
#pragma unroll
            for (int j = 0; j < 8; ++j) acc[j] += __shfl_xor(acc[j], m);
    }

    float den[HH];
#pragma unroll
    for (int h = 0; h < HH; ++h) {
        float sl = s_lane[h];
#pragma unroll
        for (int m = 1; m < 64; m <<= 1) sl += __shfl_xor(sl, m);
        den[h] = sl + 1e-16f;
    }

    if (lane < TPE) {
        float inv = 1.0f / den[hc];
        float4 b0 = *(const float4*)(bias + c8);
        float4 b1 = *(const float4*)(bias + c8 + 4);
        float bb[8] = {b0.x, b0.y, b0.z, b0.w, b1.x, b1.y, b1.z, b1.w};
        float rr[8];
#pragma unroll
        for (int j = 0; j < 8; ++j) {
            float r = acc[j] * inv + bb[j];
            if (act == 1) r = fmaxf(r, 0.f);
            else if (act == 2) r = tanhf(r);
            rr[j] = r;
        }
        if constexpr (FUSE) {
#pragma unroll
            for (int j = 0; j < 8; ++j) sHA[wid][c8 + j] = rr[j];
        } else {
            short8v o;
#pragma unroll
            for (int j = 0; j < 8; ++j)
                o[j] = (short)__bfloat16_as_ushort(__float2bfloat16(rr[j]));
            *(short8v*)(out + (long)d * HC + c8) = o;
        }
    }

    if constexpr (FUSE) {
        if (lane < 40) {
            float o = bcf[lane];
#pragma unroll 8
            for (int c = 0; c < 64; ++c) o += sHA[wid][c] * sWc[c * 40 + lane];
            outf[(long)d * 40 + lane] = o;
        }
    }
}

// ---------------- launch ----------------

extern "C" void kernel_launch(void* const* d_in, const int* in_sizes, int n_in,
                              void* d_out, int out_size, void* d_ws, size_t ws_size,
                              hipStream_t stream) {
    const float* x    = (const float*)d_in[0];
    const int*   ei   = (const int*)d_in[1];
    const float* W1   = (const float*)d_in[2];
    const float* a1s  = (const float*)d_in[3];
    const float* a1d  = (const float*)d_in[4];
    const float* b1   = (const float*)d_in[5];
    const float* W2   = (const float*)d_in[6];
    const float* a2s  = (const float*)d_in[7];
    const float* a2d  = (const float*)d_in[8];
    const float* b2   = (const float*)d_in[9];
    const float* W3   = (const float*)d_in[10];
    const float* a3s  = (const float*)d_in[11];
    const float* a3d  = (const float*)d_in[12];
    const float* b3   = (const float*)d_in[13];
    const float* Wc   = (const float*)d_in[14];
    const float* bc   = (const float*)d_in[15];

    const int F0 = 256;
    int N = in_sizes[0] / F0;          // 50000
    int E = in_sizes[1] / 2;           // 800000
    int Etot = E + N;
    const int* srcI = ei;
    const int* dstI = ei + E;

    // ---- workspace carve ----
    char* p = (char*)d_ws;
    auto alloc = [&](size_t bytes) { void* r = p; p += (bytes + 255) & ~(size_t)255; return r; };
    __hip_bfloat16* xb  = (__hip_bfloat16*)alloc((size_t)N * 256 * 2);
    __hip_bfloat16* Hb  = (__hip_bfloat16*)alloc((size_t)N * 384 * 2);
    __hip_bfloat16* O1  = (__hip_bfloat16*)alloc((size_t)N * 384 * 2);
    __hip_bfloat16* O2  = (__hip_bfloat16*)alloc((size_t)N * 128 * 2);
    __hip_bfloat16* W1T = (__hip_bfloat16*)alloc((size_t)(384 + 8) * 256 * 2);
    __hip_bfloat16* W2T = (__hip_bfloat16*)alloc((size_t)(128 + 2) * 384 * 2);
    __hip_bfloat16* W3T = (__hip_bfloat16*)alloc((size_t)(64 + 2) * 128 * 2);
    float* as_  = (float*)alloc((size_t)N * 4 * 4);
    float* ad_  = (float*)alloc((size_t)N * 4 * 4);
    int* rowptr = (int*)alloc((size_t)(N + 1) * 4);
    int* cnt    = (int*)alloc((size_t)N * 4);
    int* esrc   = (int*)alloc((size_t)Etot * 4);
    int* bsum   = (int*)alloc(256 * 4);

    // ---- merged prep (x cast + weights + projections + cnt zero) ----
    long nx4 = (long)N * 256 / 4;                 // 3.2M
    long ptot = nx4 + 158720 + N;
    prep_all<<<(int)((ptot + 255) / 256), 256, 0, stream>>>(
        x, xb, nx4, W1, a1s, a1d, W2, a2s, a2d, W3, a3s, a3d,
        W1T, W2T, W3T, cnt, N);

    // ---- CSR build (5 dispatches) ----
    int nb = (N + 255) / 256;
    hist_kernel<<<(Etot + 255) / 256, 256, 0, stream>>>(dstI, cnt, E, Etot);
    scan1<<<nb, 256, 0, stream>>>(cnt, rowptr, bsum, N);
    scan2<<<1, 256, 0, stream>>>(bsum, nb);
    scan3<<<nb, 256, 0, stream>>>(rowptr, bsum, cnt, N, Etot);
    fill_kernel<<<(Etot + 255) / 256, 256, 0, stream>>>(srcI, dstI, rowptr, cnt, esrc, E, Etot);

    auto run_gemm = [&](const __hip_bfloat16* X, int Fin, const __hip_bfloat16* WT,
                        int Hh, int C, __hip_bfloat16* Hout) {
        int HC = Hh * C;
        int Nlog = HC + 2 * Hh;
        dim3 gg((Nlog + 63) / 64, (N + 127) / 128);
        gemm_bf16<<<gg, 256, 0, stream>>>(X, WT, Hout, as_, ad_, N, Fin, Nlog, HC, Hh);
    };
    int gwb = (N + 3) / 4;   // 4 nodes (waves) per block
    float* out = (float*)d_out;

    // Layer 1: 256 -> 4x96, relu
    run_gemm(xb, 256, W1T, 4, 96, Hb);
    gat_gather_wave<4, 96, false><<<gwb, 256, 0, stream>>>(
        rowptr, esrc, Hb, as_, ad_, b1, O1, 1, N, nullptr, nullptr, nullptr);
    // Layer 2: 384 -> 1x128, tanh
    run_gemm(O1, 384, W2T, 1, 128, Hb);
    gat_gather_wave<1, 128, false><<<gwb, 256, 0, stream>>>(
        rowptr, esrc, Hb, as_, ad_, b2, O2, 2, N, nullptr, nullptr, nullptr);
    // Layer 3: 128 -> 1x64, tanh + fused classifier (64x40 matvec, f32 out)
    run_gemm(O2, 128, W3T, 1, 64, Hb);
    gat_gather_wave<1, 64, true><<<gwb, 256, 0, stream>>>(
        rowptr, esrc, Hb, as_, ad_, b3, nullptr, 2, N, Wc, bc, out);
}